// Round 14
// baseline (331.424 us; speedup 1.0000x reference)
//
#include <hip/hip_runtime.h>
#include <stdint.h>

// R20: base = R19 except BOTH gemms replaced by gemm256 — a 256x256-tile,
// BK=64, 8-wave (2Mx4N), double-buffered, counted-vmcnt GEMM:
//   per K-tile: vmcnt(8) -> raw barrier -> 4 phases {4 ds_read_b128 +
//   setprio(1) 16 MFMA setprio(0)} -> raw barrier -> issue 8 gload16 for
//   tile kt+2 (lands under a full tile of compute; vmcnt never 0 mid-loop).
// LDS image uses the R15-proven chunk-XOR swizzle (row-stride 128B,
// chunk^(row&7)), staged via pre-swizzled GLOBAL source + linear
// global_load_lds dest (rule #21). 128KB LDS (m201 precedent), ~195 VGPR,
// no launch_bounds cap (R13 lesson). Grids 192/128 = 1 clean round each.
// attn/cvt_all/kvtrans = R19 verbatim.

typedef unsigned short u16;
typedef short bf16x8 __attribute__((ext_vector_type(8)));
typedef float f32x4 __attribute__((ext_vector_type(4)));

#define D_MODEL 2048
#define QKV_DIM 3072
#define NUM_HEADS 32
#define HEAD_DIM 64
#define SEQ 2048
#define MTOT 4096

static __device__ __forceinline__ u16 f2bf(float f){
  uint32_t u = __builtin_bit_cast(uint32_t, f);
  u += 0x7FFFu + ((u >> 16) & 1u);
  return (u16)(u >> 16);
}

static __device__ __forceinline__ float exp2_fast(float x){
  float r;
  asm("v_exp_f32 %0, %1" : "=v"(r) : "v"(x));
  return r;
}

static __device__ __forceinline__ uint32_t cvt_pk_bf16(float lo, float hi){
  uint32_t r;
  asm("v_cvt_pk_bf16_f32 %0, %1, %2" : "=v"(r) : "v"(lo), "v"(hi));
  return r;
}

static __device__ __forceinline__ void gload16(const u16* g, u16* l){
  __builtin_amdgcn_global_load_lds(
      (__attribute__((address_space(1))) uint32_t*)(uintptr_t)g,
      (__attribute__((address_space(3))) uint32_t*)l,
      16, 0, 0);
}

static __device__ __forceinline__ void cvt8(const float* __restrict__ src,
                                            u16* __restrict__ dst,
                                            int i, float scl){
  float4 a = *(const float4*)(src + i);
  float4 b = *(const float4*)(src + i + 4);
  union { u16 h[8]; uint4 v; } t;
  t.h[0]=f2bf(a.x*scl); t.h[1]=f2bf(a.y*scl); t.h[2]=f2bf(a.z*scl); t.h[3]=f2bf(a.w*scl);
  t.h[4]=f2bf(b.x*scl); t.h[5]=f2bf(b.y*scl); t.h[6]=f2bf(b.z*scl); t.h[7]=f2bf(b.w*scl);
  *(uint4*)(dst + i) = t.v;
}

__global__ __launch_bounds__(256)
void cvt_bf16(const float* __restrict__ in, u16* __restrict__ out, int n,
              float scl){
  const int i = (blockIdx.x * 256 + threadIdx.x) * 8;
  if (i >= n) return;
  cvt8(in, out, i, scl);
}

// Fused conversion of all inputs: block-range dispatch (uniform branch).
__global__ __launch_bounds__(256)
void cvt_all(const float* __restrict__ x,  const float* __restrict__ Wq,
             const float* __restrict__ Wk, const float* __restrict__ Wv,
             const float* __restrict__ Wo,
             u16* __restrict__ xb, u16* __restrict__ Wb,
             u16* __restrict__ Wob, float qscl){
  const int bid = blockIdx.x;
  const float* src; u16* dst; int off; float scl = 1.0f;
  if (bid < 4096){        src = x;  dst = xb;                              off = bid;        }
  else if (bid < 6144){   src = Wq; dst = Wb;                              off = bid - 4096; scl = qscl; }
  else if (bid < 6656){   src = Wk; dst = Wb + (size_t)D_MODEL*D_MODEL;    off = bid - 6144; }
  else if (bid < 7168){   src = Wv; dst = Wb + (size_t)2560*D_MODEL;       off = bid - 6656; }
  else {                  src = Wo; dst = Wob;                             off = bid - 7168; }
  const int i = (off * 256 + threadIdx.x) * 8;
  cvt8(src, dst, i, scl);
}

// C[M,N] = A[M,K] @ B[N,K]^T. 256x256 tile, BK=64, 8 waves (2Mx4N),
// double-buffered LDS with counted vmcnt(8) (never 0 mid-loop), chunk-XOR
// swizzled LDS image staged via pre-swizzled global src + linear gload_lds.
template <bool F32OUT>
__global__ __launch_bounds__(512)
void gemm256(const u16* __restrict__ A, const u16* __restrict__ B,
             void* __restrict__ Cv, int M, int N, int K, int nbx){
  __shared__ __attribute__((aligned(16))) u16 As[2][256*64];
  __shared__ __attribute__((aligned(16))) u16 Bs[2][256*64];
  const int tid = threadIdx.x;
  const int wid = tid >> 6, lane = tid & 63;
  const int quad = lane >> 4, l16 = lane & 15;
  const int wr = wid >> 2, wc = wid & 3;          // 2(M) x 4(N) wave grid
  const int sw8 = l16 & 7;
  // bijective XCD swizzle (nwg % 8 == 0 for both grids)
  const int nwg = gridDim.x;
  const int qq = nwg >> 3, rr = nwg & 7;
  const int xcd = blockIdx.x & 7, lin = blockIdx.x >> 3;
  const int swz = (xcd < rr ? xcd*(qq+1) : rr*(qq+1) + (xcd-rr)*qq) + lin;
  const int m0 = (swz / nbx) * 256, n0 = (swz % nbx) * 256;

  const f32x4 zero = {0.f, 0.f, 0.f, 0.f};
  f32x4 acc[8][4];
#pragma unroll
  for (int i = 0; i < 8; i++)
#pragma unroll
    for (int j = 0; j < 4; j++) acc[i][j] = zero;

  const int NT = K >> 6;

  // stage K-tile kt into buffer c: 8 gload16/thread; LDS dest linear
  // (wave-uniform base + lane*16), global source col pre-swizzled so the
  // LDS image has chunk' = chunk ^ (row & 7).
#define STAGE(kt_, c_)                                                      \
  {                                                                         \
    const int k0_ = (kt_) << 6;                                             \
    _Pragma("unroll")                                                       \
    for (int t = 0; t < 4; ++t){                                            \
      const int L = t*512 + tid;                                            \
      const int r_ = L >> 3, c8_ = L & 7;                                   \
      gload16(A + (size_t)(m0 + r_)*K + k0_ + ((c8_ ^ (r_ & 7)) << 3),      \
              (u16*)&As[c_][(t*512 + wid*64) * 8]);                         \
      gload16(B + (size_t)(n0 + r_)*K + k0_ + ((c8_ ^ (r_ & 7)) << 3),      \
              (u16*)&Bs[c_][(t*512 + wid*64) * 8]);                         \
    }                                                                       \
  }

  STAGE(0, 0);
  STAGE(1, 1);

  for (int kt = 0; kt < NT; ++kt){
    const int c = kt & 1;
    // wait for tile kt's 8 loads (8 of tile kt+1 may stay in flight)
    if (kt < NT - 1) asm volatile("s_waitcnt vmcnt(8)" ::: "memory");
    else             asm volatile("s_waitcnt vmcnt(0)" ::: "memory");
    __builtin_amdgcn_s_barrier();            // all waves' tile-kt data visible
    __builtin_amdgcn_sched_barrier(0);

    const u16* Ab = As[c];
    const u16* Bb = Bs[c];
    bf16x8 bfr[4][2];
#pragma unroll
    for (int n = 0; n < 4; ++n)
#pragma unroll
      for (int kk = 0; kk < 2; ++kk)
        bfr[n][kk] = *(const bf16x8*)(Bb + (wc*64 + n*16 + l16)*64 +
                                      (((kk*4 + quad) ^ sw8) << 3));
#pragma unroll
    for (int p = 0; p < 4; ++p){
      bf16x8 af[2][2];
#pragma unroll
      for (int mm = 0; mm < 2; ++mm)
#pragma unroll
        for (int kk = 0; kk < 2; ++kk)
          af[mm][kk] = *(const bf16x8*)(Ab + (wr*128 + (p*2+mm)*16 + l16)*64 +
                                        (((kk*4 + quad) ^ sw8) << 3));
      __builtin_amdgcn_s_setprio(1);
#pragma unroll
      for (int mm = 0; mm < 2; ++mm)
#pragma unroll
        for (int n = 0; n < 4; ++n)
#pragma unroll
          for (int kk = 0; kk < 2; ++kk)
            acc[p*2+mm][n] = __builtin_amdgcn_mfma_f32_16x16x32_bf16(
                af[mm][kk], bfr[n][kk], acc[p*2+mm][n], 0, 0, 0);
      __builtin_amdgcn_s_setprio(0);
    }
    __builtin_amdgcn_sched_barrier(0);
    __builtin_amdgcn_s_barrier();            // all waves done reading buf c
    if (kt + 2 < NT) STAGE(kt + 2, c);       // lands under tile kt+1 compute
  }
#undef STAGE

#pragma unroll
  for (int mf = 0; mf < 8; ++mf)
#pragma unroll
    for (int n = 0; n < 4; ++n){
      const int col = n0 + wc*64 + n*16 + l16;
#pragma unroll
      for (int r = 0; r < 4; ++r){
        const int row = m0 + wr*128 + mf*16 + quad*4 + r;
        if constexpr (F32OUT)
          ((float*)Cv)[(size_t)row*N + col] = acc[mf][n][r];
        else
          ((u16*)Cv)[(size_t)row*N + col] = f2bf(acc[mf][n][r]);
      }
    }
}

// kvtrans: per-(b,hk,j) 8KB K/V tiles in the exact swizzled LDS image.
__global__ __launch_bounds__(256)
void kvtrans(const u16* __restrict__ QKV, u16* __restrict__ Ksw,
             u16* __restrict__ Vsw){
  __shared__ u16 Ls[64*72];
  const int tid = threadIdx.x;
  const int st = blockIdx.x, hk = blockIdx.y, b = blockIdx.z;
  const size_t rb = (size_t)b * SEQ;
  const size_t tbase = ((size_t)(b*8 + hk)*32 + st) * 4096;

#pragma unroll
  for (int t = 0; t < 2; t++){
    const int task = t*256 + tid;
    const int r = task >> 3, c = task & 7;
    uint4 kv = *(const uint4*)(QKV + (rb + st*64 + r)*QKV_DIM + 2048 + hk*HEAD_DIM + c*8);
    *(uint4*)(Ksw + tbase + r*64 + (size_t)((c ^ (r & 7)) * 8)) = kv;
  }
#pragma unroll
  for (int t = 0; t < 2; t++){
    const int task = t*256 + tid;
    const int r = task >> 3, c = task & 7;
    *(uint4*)(Ls + r*72 + c*8) =
        *(const uint4*)(QKV + (rb + st*64 + r)*QKV_DIM + 2560 + hk*HEAD_DIM + c*8);
  }
  __syncthreads();
#pragma unroll
  for (int t = 0; t < 2; t++){
    const int task = t*256 + tid;
    const int d = task >> 3, sc = task & 7;
    union { u16 h[8]; uint4 v; } tmp;
#pragma unroll
    for (int e = 0; e < 8; e++){
      const int key = ((2*(sc>>2) + (e>>2))<<4) + ((sc&3)<<2) + (e&3);
      tmp.h[e] = Ls[key*72 + d];
    }
    *(uint4*)(Vsw + tbase + d*64 + (size_t)((sc ^ (d & 7)) * 8)) = tmp.v;
  }
}

// attn (R17/R19 verbatim): swapped QK^T, in-register P, log2 softmax +
// defer-max, complement-balanced qt, dbuf gload_lds staging, XOR reads.
__global__ __launch_bounds__(256)
void attn(const u16* __restrict__ Q, const u16* __restrict__ Ksw,
          const u16* __restrict__ Vsw, u16* __restrict__ O, int qs){
  __shared__ __attribute__((aligned(16))) u16 Ks[2][64*64];
  __shared__ __attribute__((aligned(16))) u16 Vt[2][64*64];
  const int tid = threadIdx.x;
  const int wave = tid >> 6, lane = tid & 63, quad = lane >> 4, l16 = lane & 15;
  const int g_ = (blockIdx.x + blockIdx.y) & 31;
  const int qt = blockIdx.z ? (31 - g_) : g_;
  const int h = blockIdx.y, b = blockIdx.z;
  const int hk = h >> 2;
  const size_t rb = (size_t)b * SEQ;
  const size_t hb = ((size_t)(b*8 + hk)) * 32;

  const int qrow = wave*16 + l16;
  const int sw = l16 & 7;

  bf16x8 qf[2];
  {
    const u16* qp = Q + (rb + qt*64 + wave*16 + l16)*qs + h*HEAD_DIM;
    qf[0] = *(const bf16x8*)(qp + quad*8);
    qf[1] = *(const bf16x8*)(qp + 32 + quad*8);
  }
  const f32x4 zero = {0.f, 0.f, 0.f, 0.f};
  f32x4 oacc[4];
#pragma unroll
  for (int i = 0; i < 4; i++) oacc[i] = zero;
  float m_i = -INFINITY;
  float l_i = 0.f;

  {
    const u16* kt = Ksw + hb * 4096;
    const u16* vt = Vsw + hb * 4096;
#pragma unroll
    for (int t = 0; t < 2; t++){
      const int ch = wave*2 + t;
      gload16(kt + ch*512 + lane*8, &Ks[0][ch*512]);
      gload16(vt + ch*512 + lane*8, &Vt[0][ch*512]);
    }
  }
  int cur = 0;

  for (int j = 0; j <= qt; ++j){
    __syncthreads();
    if (j < qt){
      const u16* kt = Ksw + (hb + j + 1) * 4096;
      const u16* vt = Vsw + (hb + j + 1) * 4096;
#pragma unroll
      for (int t = 0; t < 2; t++){
        const int ch = wave*2 + t;
        gload16(kt + ch*512 + lane*8, &Ks[cur^1][ch*512]);
        gload16(vt + ch*512 + lane*8, &Vt[cur^1][ch*512]);
      }
    }
    const u16* Ksb = Ks[cur];
    const u16* Vtb = Vt[cur];

    f32x4 st[4];
#pragma unroll
    for (int ni = 0; ni < 4; ni++){
      f32x4 s = zero;
#pragma unroll
      for (int ss = 0; ss < 2; ss++){
        bf16x8 kf = *(const bf16x8*)(Ksb + ((ni*16 + l16) << 6) +
                                     (((ss*4 + quad) ^ sw) << 3));
        s = __builtin_amdgcn_mfma_f32_16x16x32_bf16(kf, qf[ss], s, 0, 0, 0);
      }
      st[ni] = s;
    }
    if (j == qt){
#pragma unroll
      for (int ni = 0; ni < 4; ni++)
#pragma unroll
        for (int r = 0; r < 4; r++)
          if (ni*16 + quad*4 + r > qrow) st[ni][r] = -INFINITY;
    }

    float mx = fmaxf(fmaxf(fmaxf(st[0][0], st[0][1]), fmaxf(st[0][2], st[0][3])),
                     fmaxf(fmaxf(st[1][0], st[1][1]), fmaxf(st[1][2], st[1][3])));
    mx = fmaxf(mx, fmaxf(fmaxf(fmaxf(st[2][0], st[2][1]), fmaxf(st[2][2], st[2][3])),
                         fmaxf(fmaxf(st[3][0], st[3][1]), fmaxf(st[3][2], st[3][3]))));
    mx = fmaxf(mx, __shfl_xor(mx, 16));
    mx = fmaxf(mx, __shfl_xor(mx, 32));

    if (__all(mx <= m_i + 10.f)){
      float ps = 0.f;
#pragma unroll
      for (int ni = 0; ni < 4; ni++)
#pragma unroll
        for (int r = 0; r < 4; r++){
          const float p = exp2_fast(st[ni][r] - m_i);
          st[ni][r] = p;
          ps += p;
        }
      ps += __shfl_xor(ps, 16);
      ps += __shfl_xor(ps, 32);
      l_i += ps;
    } else {
      const float mn = fmaxf(m_i, mx);
      const float alpha = exp2_fast(m_i - mn);
      float ps = 0.f;
#pragma unroll
      for (int ni = 0; ni < 4; ni++)
#pragma unroll
        for (int r = 0; r < 4; r++){
          const float p = exp2_fast(st[ni][r] - mn);
          st[ni][r] = p;
          ps += p;
        }
      ps += __shfl_xor(ps, 16);
      ps += __shfl_xor(ps, 32);
      l_i = l_i*alpha + ps;
      m_i = mn;
      float ar[4];
#pragma unroll
      for (int r = 0; r < 4; r++) ar[r] = __shfl(alpha, quad*4 + r);
#pragma unroll
      for (int ci = 0; ci < 4; ci++)
#pragma unroll
        for (int r = 0; r < 4; r++) oacc[ci][r] *= ar[r];
    }

    bf16x8 pfr[2];
#pragma unroll
    for (int ss = 0; ss < 2; ss++){
      union { uint32_t w[4]; bf16x8 v; } pk;
      pk.w[0] = cvt_pk_bf16(st[2*ss][0],   st[2*ss][1]);
      pk.w[1] = cvt_pk_bf16(st[2*ss][2],   st[2*ss][3]);
      pk.w[2] = cvt_pk_bf16(st[2*ss+1][0], st[2*ss+1][1]);
      pk.w[3] = cvt_pk_bf16(st[2*ss+1][2], st[2*ss+1][3]);
      pfr[ss] = pk.v;
    }

#pragma unroll
    for (int ss = 0; ss < 2; ss++)
#pragma unroll
      for (int ci = 0; ci < 4; ci++){
        bf16x8 vf = *(const bf16x8*)(Vtb + ((ci*16 + l16) << 6) +
                                     (((ss*4 + quad) ^ sw) << 3));
        oacc[ci] = __builtin_amdgcn_mfma_f32_16x16x32_bf16(pfr[ss], vf, oacc[ci], 0, 0, 0);
      }
    cur ^= 1;
  }

  float lf[4];
#pragma unroll
  for (int r = 0; r < 4; r++) lf[r] = __shfl(l_i, quad*4 + r);
#pragma unroll
  for (int ci = 0; ci < 4; ci++)
#pragma unroll
    for (int r = 0; r < 4; r++){
      const size_t row = rb + qt*64 + wave*16 + quad*4 + r;
      O[row*D_MODEL + h*HEAD_DIM + ci*16 + l16] = f2bf(oacc[ci][r] / lf[r]);
    }
}

extern "C" void kernel_launch(void* const* d_in, const int* in_sizes, int n_in,
                              void* d_out, int out_size, void* d_ws, size_t ws_size,
                              hipStream_t stream){
  const float* x  = (const float*)d_in[0];
  const float* Wq = (const float*)d_in[1];
  const float* Wk = (const float*)d_in[2];
  const float* Wv = (const float*)d_in[3];
  const float* Wo = (const float*)d_in[4];
  float* out = (float*)d_out;

  u16* xb   = (u16*)d_ws;                    // x / later attn-out  [4096,2048]
  u16* Wb   = xb + (size_t)MTOT*D_MODEL;     // fused weights [3072,2048]
  u16* Wob  = Wb + (size_t)QKV_DIM*D_MODEL;  // Wo bf16 [2048,2048] (if ws fits)
  u16* QKVb = (u16*)d_out;                   // QKV scratch [4096,3072] bf16
  u16* Kswz = Wb;                            // swizzled K tiles (Wq region, dead after gemm1)
  u16* Vswz = Wb + (size_t)2*1024*1024;      // swizzled V tiles

  const int nwq = D_MODEL*D_MODEL;
  const float QSCL = 0.125f * 1.44269504f;   // softmax scale * log2(e)

  const size_t ws_need = ((size_t)MTOT*D_MODEL + (size_t)QKV_DIM*D_MODEL +
                          (size_t)D_MODEL*D_MODEL) * sizeof(u16);
  const bool wob_fits = (ws_size >= ws_need);

  if (wob_fits){
    cvt_all<<<9216, 256, 0, stream>>>(x, Wq, Wk, Wv, Wo, xb, Wb, Wob, QSCL);
  } else {
    cvt_all<<<7168, 256, 0, stream>>>(x, Wq, Wk, Wv, Wo, xb, Wb, Wob, QSCL);
  }
  gemm256<false><<<(QKV_DIM/256)*(MTOT/256), 512, 0, stream>>>(
      xb, Wb, QKVb, MTOT, QKV_DIM, D_MODEL, QKV_DIM/256);
  kvtrans<<<dim3(SEQ/64, 8, 2), 256, 0, stream>>>(QKVb, Kswz, Vswz);
  attn<<<dim3(SEQ/64, NUM_HEADS, 2), 256, 0, stream>>>(
      QKVb, Kswz, Vswz, xb, QKV_DIM);
  const u16* Bw2;
  if (wob_fits){
    Bw2 = Wob;
  } else {
    cvt_bf16<<<nwq/2048, 256, 0, stream>>>(Wo, Wb, nwq, 1.0f);
    Bw2 = Wb;
  }
  gemm256<true><<<(D_MODEL/256)*(MTOT/256), 512, 0, stream>>>(
      xb, Bw2, (void*)out, MTOT, D_MODEL, D_MODEL, D_MODEL/256);
}